// Round 1
// baseline (1136.415 us; speedup 1.0000x reference)
//
#include <hip/hip_runtime.h>
#include <math.h>

#define NN 20000
#define NE 320000
#define IN_DIM 16
#define HID 64
#define HEADS 4
#define HD 256          // HEADS*HID
#define OUTW 208        // 16 + 3*64
#define NEG 0.2f

// ---------------- embed: feat = node_feat @ W_embed + b; also write out cols 0..79
__global__ void k_embed(const float* __restrict__ nf, const float* __restrict__ We,
                        const float* __restrict__ be, float* __restrict__ feat,
                        float* __restrict__ out) {
  int tid = blockIdx.x * blockDim.x + threadIdx.x;   // NN*64 threads
  int n = tid >> 6, c = tid & 63;
  if (n >= NN) return;
  float acc = be[c];
#pragma unroll
  for (int k = 0; k < IN_DIM; ++k)
    acc += nf[n * IN_DIM + k] * We[k * HID + c];
  feat[n * HID + c] = acc;
  out[n * OUTW + 16 + c] = acc;
  if (c < IN_DIM) out[n * OUTW + c] = nf[n * IN_DIM + c];
}

// ---------------- CSR build over dst
__global__ void k_count(const int* __restrict__ dst, int* __restrict__ counts) {
  int e = blockIdx.x * blockDim.x + threadIdx.x;
  if (e < NE) atomicAdd(&counts[dst[e]], 1);
}

__global__ void k_scan(const int* __restrict__ counts, int* __restrict__ rowptr) {
  __shared__ int sm[1024];
  __shared__ int running;
  if (threadIdx.x == 0) { running = 0; rowptr[0] = 0; }
  __syncthreads();
  for (int base = 0; base < NN; base += 1024) {
    int i = base + threadIdx.x;
    int v = (i < NN) ? counts[i] : 0;
    sm[threadIdx.x] = v;
    __syncthreads();
    for (int off = 1; off < 1024; off <<= 1) {
      int t = (threadIdx.x >= off) ? sm[threadIdx.x - off] : 0;
      __syncthreads();
      sm[threadIdx.x] += t;
      __syncthreads();
    }
    if (i < NN) rowptr[i + 1] = running + sm[threadIdx.x];
    __syncthreads();
    if (threadIdx.x == 0) running += sm[1023];
    __syncthreads();
  }
}

__global__ void k_scatter(const int* __restrict__ dst, const int* __restrict__ rowptr,
                          int* __restrict__ cursor, int* __restrict__ eidx) {
  int e = blockIdx.x * blockDim.x + threadIdx.x;
  if (e >= NE) return;
  int d = dst[e];
  int pos = rowptr[d] + atomicAdd(&cursor[d], 1);
  eidx[pos] = e;
}

// ---------------- node projections: fni (+b_att folded), fnj, hn
// block = 256 threads, 8 nodes per block; thread c handles output column c for all 8.
__global__ __launch_bounds__(256) void k_nodeproj(
    const float* __restrict__ feat, const float* __restrict__ Wni,
    const float* __restrict__ Wnj, const float* __restrict__ Wnd,
    const float* __restrict__ batt, float* __restrict__ fni,
    float* __restrict__ fnj, float* __restrict__ hn) {
  __shared__ float hs[8 * HID];
  int n0 = blockIdx.x * 8;
  int c = threadIdx.x;
  for (int i = threadIdx.x; i < 8 * HID; i += 256)
    hs[i] = feat[(n0 + (i >> 6)) * HID + (i & 63)];
  __syncthreads();
  float aI[8] = {0}, aJ[8] = {0}, aN[8] = {0};
  for (int k = 0; k < HID; ++k) {
    float wi = Wni[k * HD + c], wj = Wnj[k * HD + c], wn = Wnd[k * HD + c];
#pragma unroll
    for (int t = 0; t < 8; ++t) {
      float x = hs[t * HID + k];
      aI[t] += x * wi; aJ[t] += x * wj; aN[t] += x * wn;
    }
  }
  float b = batt[c];
#pragma unroll
  for (int t = 0; t < 8; ++t) {
    int n = n0 + t;
    fni[n * HD + c] = aI[t] + b;
    fnj[n * HD + c] = aJ[t];
    hn[n * HD + c]  = aN[t];
  }
}

// ---------------- edge logits: f_out = lrelu(fni[src]+fnj[dst]+ef@Wf), e = <f_out, attn>
// block = 256 (4 waves), W_fij staged in LDS (64KB), 8 edges per wave-chunk.
__global__ __launch_bounds__(256) void k_edgelogits(
    const float* __restrict__ ef, const int* __restrict__ src,
    const int* __restrict__ dst, const float* __restrict__ fni,
    const float* __restrict__ fnj, const float* __restrict__ Wf,
    const float* __restrict__ attnL, float* __restrict__ elog) {
  __shared__ float Wl[HID * HD];
  for (int i = threadIdx.x; i < HID * HD; i += 256) Wl[i] = Wf[i];
  __syncthreads();
  int w = threadIdx.x >> 6;
  int j = threadIdx.x & 63;
  float4 at4 = *reinterpret_cast<const float4*>(&attnL[4 * j]);
  const int CHUNKS = NE / 32;  // 10000
  for (int ch = blockIdx.x; ch < CHUNKS; ch += gridDim.x) {
    int e0 = ch * 32 + w * 8;
    float xv[8];
#pragma unroll
    for (int t = 0; t < 8; ++t) xv[t] = ef[(e0 + t) * HID + j];
    float4 acc[8];
#pragma unroll
    for (int t = 0; t < 8; ++t) {
      int e = e0 + t;
      int s = src[e], d = dst[e];
      float4 a = *reinterpret_cast<const float4*>(&fni[s * HD + 4 * j]);
      float4 b = *reinterpret_cast<const float4*>(&fnj[d * HD + 4 * j]);
      acc[t].x = a.x + b.x; acc[t].y = a.y + b.y;
      acc[t].z = a.z + b.z; acc[t].w = a.w + b.w;
    }
    for (int k = 0; k < HID; ++k) {
      float4 wr = *reinterpret_cast<const float4*>(&Wl[k * HD + 4 * j]);
#pragma unroll
      for (int t = 0; t < 8; ++t) {
        float xk = __shfl(xv[t], k);
        acc[t].x += xk * wr.x; acc[t].y += xk * wr.y;
        acc[t].z += xk * wr.z; acc[t].w += xk * wr.w;
      }
    }
#pragma unroll
    for (int t = 0; t < 8; ++t) {
      float4 v = acc[t];
      v.x = v.x > 0.f ? v.x : NEG * v.x;
      v.y = v.y > 0.f ? v.y : NEG * v.y;
      v.z = v.z > 0.f ? v.z : NEG * v.z;
      v.w = v.w > 0.f ? v.w : NEG * v.w;
      float p = v.x * at4.x + v.y * at4.y + v.z * at4.z + v.w * at4.w;
      p += __shfl_xor(p, 1);
      p += __shfl_xor(p, 2);
      p += __shfl_xor(p, 4);
      p += __shfl_xor(p, 8);
      if ((j & 15) == 0) elog[(e0 + t) * HEADS + (j >> 4)] = p;
    }
  }
}

// ---------------- per-(node,head) edge softmax, normalized in place
__global__ void k_softmax(const int* __restrict__ rowptr, const int* __restrict__ eidx,
                          float* __restrict__ elog) {
  int t = blockIdx.x * blockDim.x + threadIdx.x;
  if (t >= NN * HEADS) return;
  int n = t >> 2, h = t & 3;
  int s0 = rowptr[n], s1 = rowptr[n + 1];
  float m = -1e30f;
  for (int i = s0; i < s1; ++i) m = fmaxf(m, elog[eidx[i] * HEADS + h]);
  float z = 0.f;
  for (int i = s0; i < s1; ++i) {
    float v = __expf(elog[eidx[i] * HEADS + h] - m);
    elog[eidx[i] * HEADS + h] = v;
    z += v;
  }
  if (z > 0.f) {
    float inv = 1.0f / z;
    for (int i = s0; i < s1; ++i) elog[eidx[i] * HEADS + h] *= inv;
  }
}

// ---------------- aggregation: one wave per node, agg[n] = sum_e a[e]*hn[src[e]]
__global__ __launch_bounds__(256) void k_agg(
    const int* __restrict__ rowptr, const int* __restrict__ eidx,
    const int* __restrict__ src, const float* __restrict__ elog,
    const float* __restrict__ hn, float* __restrict__ agg) {
  int gw = (blockIdx.x * blockDim.x + threadIdx.x) >> 6;
  int j = threadIdx.x & 63;
  if (gw >= NN) return;
  int n = gw;
  int s0 = rowptr[n], s1 = rowptr[n + 1];
  int h = j >> 4;
  float4 acc = make_float4(0.f, 0.f, 0.f, 0.f);
  for (int i = s0; i < s1; ++i) {
    int e = eidx[i];
    int s = src[e];
    float a = elog[e * HEADS + h];
    float4 v = *reinterpret_cast<const float4*>(&hn[s * HD + 4 * j]);
    acc.x += v.x * a; acc.y += v.y * a; acc.z += v.z * a; acc.w += v.w * a;
  }
  *reinterpret_cast<float4*>(&agg[n * HD + 4 * j]) = acc;
}

// ---------------- MLP + residual: feat = agg @ W_mlp + b + feat; also write out slice
// block = 256 threads = 4 waves; block handles 32 nodes (8 per wave); agg tile in LDS.
__global__ __launch_bounds__(256) void k_mlp(
    const float* __restrict__ agg, const float* __restrict__ Wm,
    const float* __restrict__ bm, float* __restrict__ feat,
    float* __restrict__ out, int outoff) {
  __shared__ float as_[32 * HD];
  int n0 = blockIdx.x * 32;
  for (int i = threadIdx.x; i < 32 * HD; i += 256) as_[i] = agg[n0 * HD + i];
  __syncthreads();
  int c = threadIdx.x & 63;
  int g = threadIdx.x >> 6;
  float acc[8] = {0};
  for (int k = 0; k < HD; ++k) {
    float wv = Wm[k * HID + c];
#pragma unroll
    for (int t = 0; t < 8; ++t)
      acc[t] += as_[(g * 8 + t) * HD + k] * wv;
  }
  float b = bm[c];
#pragma unroll
  for (int t = 0; t < 8; ++t) {
    int n = n0 + g * 8 + t;
    float v = acc[t] + b + feat[n * HID + c];
    feat[n * HID + c] = v;
    out[n * OUTW + outoff + c] = v;
  }
}

extern "C" void kernel_launch(void* const* d_in, const int* in_sizes, int n_in,
                              void* d_out, int out_size, void* d_ws, size_t ws_size,
                              hipStream_t stream) {
  const float* node_feat = (const float*)d_in[0];
  const float* edge_feat = (const float*)d_in[1];
  const int*   src       = (const int*)d_in[2];
  const int*   dst       = (const int*)d_in[3];
  const float* W_embed   = (const float*)d_in[4];
  const float* b_embed   = (const float*)d_in[5];
  const float* W_ni      = (const float*)d_in[6];
  const float* W_nj      = (const float*)d_in[7];
  const float* W_fij     = (const float*)d_in[8];
  const float* b_att     = (const float*)d_in[9];
  const float* attn      = (const float*)d_in[10];
  const float* W_node    = (const float*)d_in[11];
  const float* W_mlp     = (const float*)d_in[12];
  const float* b_mlp     = (const float*)d_in[13];
  float* out = (float*)d_out;

  // workspace layout (floats, then ints)
  float* ws   = (float*)d_ws;
  float* feat = ws;                         // NN*HID
  float* fni  = feat + (size_t)NN * HID;    // NN*HD
  float* fnj  = fni + (size_t)NN * HD;      // NN*HD
  float* hn   = fnj + (size_t)NN * HD;      // NN*HD
  float* elog = hn + (size_t)NN * HD;       // NE*HEADS
  int* counts = (int*)(elog + (size_t)NE * HEADS);  // NN
  int* rowptr = counts + NN;                // NN+1
  int* eidx   = rowptr + NN + 1;            // NE
  int* cursor = eidx + NE;                  // NN
  float* aggb = fni;                        // reuse fni after logits consumed it

  // zero counts + cursor
  hipMemsetAsync(counts, 0, sizeof(int) * NN, stream);
  hipMemsetAsync(cursor, 0, sizeof(int) * NN, stream);

  k_embed<<<(NN * 64) / 256, 256, 0, stream>>>(node_feat, W_embed, b_embed, feat, out);
  k_count<<<NE / 256, 256, 0, stream>>>(dst, counts);
  k_scan<<<1, 1024, 0, stream>>>(counts, rowptr);
  k_scatter<<<NE / 256, 256, 0, stream>>>(dst, rowptr, cursor, eidx);

  for (int L = 0; L < 2; ++L) {
    const float* WniL = W_ni + (size_t)L * HID * HD;
    const float* WnjL = W_nj + (size_t)L * HID * HD;
    const float* WfL  = W_fij + (size_t)L * HID * HD;
    const float* WndL = W_node + (size_t)L * HID * HD;
    const float* battL = b_att + (size_t)L * HD;
    const float* attnL = attn + (size_t)L * HEADS * HID;
    const float* WmL  = W_mlp + (size_t)L * HD * HID;
    const float* bmL  = b_mlp + (size_t)L * HID;

    k_nodeproj<<<NN / 8, 256, 0, stream>>>(feat, WniL, WnjL, WndL, battL, fni, fnj, hn);
    k_edgelogits<<<512, 256, 0, stream>>>(edge_feat, src, dst, fni, fnj, WfL, attnL, elog);
    k_softmax<<<(NN * HEADS + 255) / 256, 256, 0, stream>>>(rowptr, eidx, elog);
    k_agg<<<(NN * 64) / 256, 256, 0, stream>>>(rowptr, eidx, src, elog, hn, aggb);
    k_mlp<<<NN / 32, 256, 0, stream>>>(aggb, WmL, bmL, feat, out, 80 + L * 64);
  }
}

// Round 2
// 1092.084 us; speedup vs baseline: 1.0406x; 1.0406x over previous
//
#include <hip/hip_runtime.h>
#include <math.h>

#define NN 20000
#define NE 320000
#define IN_DIM 16
#define HID 64
#define HEADS 4
#define HD 256          // HEADS*HID
#define OUTW 208        // 16 + 3*64
#define NEG 0.2f

typedef unsigned short u16;
typedef unsigned int u32;

__device__ __forceinline__ float b2f(u16 u) {
  union { u32 i; float f; } c; c.i = ((u32)u) << 16; return c.f;
}
__device__ __forceinline__ u16 f2b(float f) {
  union { float f; u32 i; } c; c.f = f;
  u32 r = (c.i + 0x7FFFu + ((c.i >> 16) & 1u)) >> 16;
  return (u16)r;
}

// ---------------- embed: feat = node_feat @ W_embed + b; also write out cols 0..79
__global__ void k_embed(const float* __restrict__ nf, const float* __restrict__ We,
                        const float* __restrict__ be, float* __restrict__ feat,
                        float* __restrict__ out) {
  int tid = blockIdx.x * blockDim.x + threadIdx.x;   // NN*64 threads
  int n = tid >> 6, c = tid & 63;
  if (n >= NN) return;
  float acc = be[c];
#pragma unroll
  for (int k = 0; k < IN_DIM; ++k)
    acc += nf[n * IN_DIM + k] * We[k * HID + c];
  feat[n * HID + c] = acc;
  out[n * OUTW + 16 + c] = acc;
  if (c < IN_DIM) out[n * OUTW + c] = nf[n * IN_DIM + c];
}

// ---------------- CSR build over dst
__global__ void k_count(const int* __restrict__ dst, int* __restrict__ counts) {
  int e = blockIdx.x * blockDim.x + threadIdx.x;
  if (e < NE) atomicAdd(&counts[dst[e]], 1);
}

__global__ void k_scan(const int* __restrict__ counts, int* __restrict__ rowptr) {
  __shared__ int sm[1024];
  __shared__ int running;
  if (threadIdx.x == 0) { running = 0; rowptr[0] = 0; }
  __syncthreads();
  for (int base = 0; base < NN; base += 1024) {
    int i = base + threadIdx.x;
    int v = (i < NN) ? counts[i] : 0;
    sm[threadIdx.x] = v;
    __syncthreads();
    for (int off = 1; off < 1024; off <<= 1) {
      int t = (threadIdx.x >= off) ? sm[threadIdx.x - off] : 0;
      __syncthreads();
      sm[threadIdx.x] += t;
      __syncthreads();
    }
    if (i < NN) rowptr[i + 1] = running + sm[threadIdx.x];
    __syncthreads();
    if (threadIdx.x == 0) running += sm[1023];
    __syncthreads();
  }
}

__global__ void k_scatter(const int* __restrict__ dst, const int* __restrict__ rowptr,
                          int* __restrict__ cursor, int* __restrict__ eidx) {
  int e = blockIdx.x * blockDim.x + threadIdx.x;
  if (e >= NE) return;
  int d = dst[e];
  int pos = rowptr[d] + atomicAdd(&cursor[d], 1);
  eidx[pos] = e;
}

// ---------------- permute edges into CSR (dst-grouped) order; edge_feat -> bf16
__global__ void k_permute(const int* __restrict__ eidx, const float* __restrict__ ef,
                          const int* __restrict__ src, const int* __restrict__ dst,
                          u16* __restrict__ efp, int* __restrict__ srcp,
                          int* __restrict__ dstp) {
  int tid = blockIdx.x * blockDim.x + threadIdx.x;   // NE*64 threads
  int i = tid >> 6, c = tid & 63;
  if (i >= NE) return;
  int e = eidx[i];
  efp[i * HID + c] = f2b(ef[e * HID + c]);
  if (c == 0) { srcp[i] = src[e]; dstp[i] = dst[e]; }
}

// ---------------- node projections: fni (+b_att folded), fnj, hn -> bf16
__global__ __launch_bounds__(256) void k_nodeproj(
    const float* __restrict__ feat, const float* __restrict__ Wni,
    const float* __restrict__ Wnj, const float* __restrict__ Wnd,
    const float* __restrict__ batt, u16* __restrict__ fni,
    u16* __restrict__ fnj, u16* __restrict__ hn) {
  __shared__ float hs[8 * HID];
  int n0 = blockIdx.x * 8;
  int c = threadIdx.x;
  for (int i = threadIdx.x; i < 8 * HID; i += 256)
    hs[i] = feat[(n0 + (i >> 6)) * HID + (i & 63)];
  __syncthreads();
  float aI[8] = {0}, aJ[8] = {0}, aN[8] = {0};
  for (int k = 0; k < HID; ++k) {
    float wi = Wni[k * HD + c], wj = Wnj[k * HD + c], wn = Wnd[k * HD + c];
#pragma unroll
    for (int t = 0; t < 8; ++t) {
      float x = hs[t * HID + k];
      aI[t] += x * wi; aJ[t] += x * wj; aN[t] += x * wn;
    }
  }
  float b = batt[c];
#pragma unroll
  for (int t = 0; t < 8; ++t) {
    int n = n0 + t;
    fni[n * HD + c] = f2b(aI[t] + b);
    fnj[n * HD + c] = f2b(aJ[t]);
    hn[n * HD + c]  = f2b(aN[t]);
  }
}

// ---------------- edge logits over CSR-ordered edges
// f_out = lrelu(fni[srcp]+fnj[dstp]+efp@Wf), e = <f_out, attn>
// block = 256 (4 waves); Wf staged bf16 in LDS (32KB); 8 edges per wave.
__global__ __launch_bounds__(256) void k_edgelogits(
    const u16* __restrict__ efp, const int* __restrict__ srcp,
    const int* __restrict__ dstp, const u16* __restrict__ fni,
    const u16* __restrict__ fnj, const float* __restrict__ Wf,
    const float* __restrict__ attnL, float* __restrict__ elog) {
  __shared__ u16 Wl[HID * HD];
  for (int i = threadIdx.x; i < HID * HD; i += 256) Wl[i] = f2b(Wf[i]);
  __syncthreads();
  int w = threadIdx.x >> 6;
  int j = threadIdx.x & 63;
  float4 at4 = *reinterpret_cast<const float4*>(&attnL[4 * j]);
  const int CHUNKS = NE / 32;  // 10000
  for (int ch = blockIdx.x; ch < CHUNKS; ch += gridDim.x) {
    int i0 = ch * 32 + w * 8;
    float xv[8];
#pragma unroll
    for (int t = 0; t < 8; ++t) xv[t] = b2f(efp[(i0 + t) * HID + j]);
    float4 acc[8];
#pragma unroll
    for (int t = 0; t < 8; ++t) {
      int i = i0 + t;
      int s = srcp[i], d = dstp[i];
      ushort4 a = *reinterpret_cast<const ushort4*>(&fni[s * HD + 4 * j]);
      ushort4 b = *reinterpret_cast<const ushort4*>(&fnj[d * HD + 4 * j]);
      acc[t].x = b2f(a.x) + b2f(b.x);
      acc[t].y = b2f(a.y) + b2f(b.y);
      acc[t].z = b2f(a.z) + b2f(b.z);
      acc[t].w = b2f(a.w) + b2f(b.w);
    }
    for (int k = 0; k < HID; ++k) {
      ushort4 w4 = *reinterpret_cast<const ushort4*>(&Wl[k * HD + 4 * j]);
      float4 wr = make_float4(b2f(w4.x), b2f(w4.y), b2f(w4.z), b2f(w4.w));
#pragma unroll
      for (int t = 0; t < 8; ++t) {
        float xk = __shfl(xv[t], k);
        acc[t].x += xk * wr.x; acc[t].y += xk * wr.y;
        acc[t].z += xk * wr.z; acc[t].w += xk * wr.w;
      }
    }
#pragma unroll
    for (int t = 0; t < 8; ++t) {
      float4 v = acc[t];
      v.x = v.x > 0.f ? v.x : NEG * v.x;
      v.y = v.y > 0.f ? v.y : NEG * v.y;
      v.z = v.z > 0.f ? v.z : NEG * v.z;
      v.w = v.w > 0.f ? v.w : NEG * v.w;
      float p = v.x * at4.x + v.y * at4.y + v.z * at4.z + v.w * at4.w;
      p += __shfl_xor(p, 1);
      p += __shfl_xor(p, 2);
      p += __shfl_xor(p, 4);
      p += __shfl_xor(p, 8);
      if ((j & 15) == 0) elog[(i0 + t) * HEADS + (j >> 4)] = p;
    }
  }
}

// ---------------- per-(node,head) edge softmax over contiguous CSR range
__global__ void k_softmax(const int* __restrict__ rowptr, float* __restrict__ elog) {
  int t = blockIdx.x * blockDim.x + threadIdx.x;
  if (t >= NN * HEADS) return;
  int n = t >> 2, h = t & 3;
  int s0 = rowptr[n], s1 = rowptr[n + 1];
  float m = -1e30f;
  for (int i = s0; i < s1; ++i) m = fmaxf(m, elog[i * HEADS + h]);
  float z = 0.f;
  for (int i = s0; i < s1; ++i) {
    float v = __expf(elog[i * HEADS + h] - m);
    elog[i * HEADS + h] = v;
    z += v;
  }
  if (z > 0.f) {
    float inv = 1.0f / z;
    for (int i = s0; i < s1; ++i) elog[i * HEADS + h] *= inv;
  }
}

// ---------------- aggregation: one wave per node over contiguous CSR range
__global__ __launch_bounds__(256) void k_agg(
    const int* __restrict__ rowptr, const int* __restrict__ srcp,
    const float* __restrict__ elog, const u16* __restrict__ hn,
    float* __restrict__ agg) {
  int n = (blockIdx.x * blockDim.x + threadIdx.x) >> 6;
  int j = threadIdx.x & 63;
  if (n >= NN) return;
  int s0 = rowptr[n], s1 = rowptr[n + 1];
  int h = j >> 4;
  float4 acc = make_float4(0.f, 0.f, 0.f, 0.f);
  for (int i = s0; i < s1; ++i) {
    int s = srcp[i];
    float a = elog[i * HEADS + h];
    ushort4 v = *reinterpret_cast<const ushort4*>(&hn[s * HD + 4 * j]);
    acc.x += b2f(v.x) * a; acc.y += b2f(v.y) * a;
    acc.z += b2f(v.z) * a; acc.w += b2f(v.w) * a;
  }
  *reinterpret_cast<float4*>(&agg[n * HD + 4 * j]) = acc;
}

// ---------------- MLP + residual: feat = agg @ W_mlp + b + feat; write out slice
__global__ __launch_bounds__(256) void k_mlp(
    const float* __restrict__ agg, const float* __restrict__ Wm,
    const float* __restrict__ bm, float* __restrict__ feat,
    float* __restrict__ out, int outoff) {
  __shared__ float as_[32 * HD];
  int n0 = blockIdx.x * 32;
  for (int i = threadIdx.x; i < 32 * HD; i += 256) as_[i] = agg[n0 * HD + i];
  __syncthreads();
  int c = threadIdx.x & 63;
  int g = threadIdx.x >> 6;
  float acc[8] = {0};
  for (int k = 0; k < HD; ++k) {
    float wv = Wm[k * HID + c];
#pragma unroll
    for (int t = 0; t < 8; ++t)
      acc[t] += as_[(g * 8 + t) * HD + k] * wv;
  }
  float b = bm[c];
#pragma unroll
  for (int t = 0; t < 8; ++t) {
    int n = n0 + g * 8 + t;
    float v = acc[t] + b + feat[n * HID + c];
    feat[n * HID + c] = v;
    out[n * OUTW + outoff + c] = v;
  }
}

extern "C" void kernel_launch(void* const* d_in, const int* in_sizes, int n_in,
                              void* d_out, int out_size, void* d_ws, size_t ws_size,
                              hipStream_t stream) {
  const float* node_feat = (const float*)d_in[0];
  const float* edge_feat = (const float*)d_in[1];
  const int*   src       = (const int*)d_in[2];
  const int*   dst       = (const int*)d_in[3];
  const float* W_embed   = (const float*)d_in[4];
  const float* b_embed   = (const float*)d_in[5];
  const float* W_ni      = (const float*)d_in[6];
  const float* W_nj      = (const float*)d_in[7];
  const float* W_fij     = (const float*)d_in[8];
  const float* b_att     = (const float*)d_in[9];
  const float* attn      = (const float*)d_in[10];
  const float* W_node    = (const float*)d_in[11];
  const float* W_mlp     = (const float*)d_in[12];
  const float* b_mlp     = (const float*)d_in[13];
  float* out = (float*)d_out;

  // workspace layout
  float* ws   = (float*)d_ws;
  float* feat = ws;                                   // NN*HID f32
  u16*  fni   = (u16*)(feat + (size_t)NN * HID);      // NN*HD bf16
  u16*  fnj   = fni + (size_t)NN * HD;                // NN*HD bf16
  u16*  hn    = fnj + (size_t)NN * HD;                // NN*HD bf16
  u16*  efp   = hn + (size_t)NN * HD;                 // NE*HID bf16
  float* elog = (float*)(efp + (size_t)NE * HID);     // NE*HEADS f32
  int* counts = (int*)(elog + (size_t)NE * HEADS);    // NN
  int* rowptr = counts + NN;                          // NN+1
  int* cursor = rowptr + NN + 1;                      // NN
  int* eidx   = cursor + NN;                          // NE
  int* srcp   = eidx + NE;                            // NE
  int* dstp   = srcp + NE;                            // NE
  float* aggb = (float*)fni;  // overlay fni+fnj (exactly NN*HD f32); safe: agg
                              // is written after edgelogits consumed fni/fnj.

  hipMemsetAsync(counts, 0, sizeof(int) * NN, stream);
  hipMemsetAsync(cursor, 0, sizeof(int) * NN, stream);

  k_embed<<<(NN * 64) / 256, 256, 0, stream>>>(node_feat, W_embed, b_embed, feat, out);
  k_count<<<NE / 256, 256, 0, stream>>>(dst, counts);
  k_scan<<<1, 1024, 0, stream>>>(counts, rowptr);
  k_scatter<<<NE / 256, 256, 0, stream>>>(dst, rowptr, cursor, eidx);
  k_permute<<<((size_t)NE * 64) / 256, 256, 0, stream>>>(eidx, edge_feat, src, dst,
                                                         efp, srcp, dstp);

  for (int L = 0; L < 2; ++L) {
    const float* WniL = W_ni + (size_t)L * HID * HD;
    const float* WnjL = W_nj + (size_t)L * HID * HD;
    const float* WfL  = W_fij + (size_t)L * HID * HD;
    const float* WndL = W_node + (size_t)L * HID * HD;
    const float* battL = b_att + (size_t)L * HD;
    const float* attnL = attn + (size_t)L * HEADS * HID;
    const float* WmL  = W_mlp + (size_t)L * HD * HID;
    const float* bmL  = b_mlp + (size_t)L * HID;

    k_nodeproj<<<NN / 8, 256, 0, stream>>>(feat, WniL, WnjL, WndL, battL, fni, fnj, hn);
    k_edgelogits<<<1280, 256, 0, stream>>>(efp, srcp, dstp, fni, fnj, WfL, attnL, elog);
    k_softmax<<<(NN * HEADS + 255) / 256, 256, 0, stream>>>(rowptr, elog);
    k_agg<<<(NN * 64) / 256, 256, 0, stream>>>(rowptr, srcp, elog, hn, aggb);
    k_mlp<<<NN / 32, 256, 0, stream>>>(aggb, WmL, bmL, feat, out, 80 + L * 64);
  }
}

// Round 3
// 688.838 us; speedup vs baseline: 1.6498x; 1.5854x over previous
//
#include <hip/hip_runtime.h>
#include <math.h>

#define NN 20000
#define NE 320000
#define IN_DIM 16
#define HID 64
#define HEADS 4
#define HD 256          // HEADS*HID
#define OUTW 208        // 16 + 3*64
#define NEG 0.2f

typedef unsigned short u16;
typedef unsigned int u32;
typedef __attribute__((ext_vector_type(8))) short bf16x8;   // MFMA A/B frag
typedef __attribute__((ext_vector_type(4))) float f32x4;    // MFMA C/D frag

__device__ __forceinline__ float b2f(u16 u) {
  union { u32 i; float f; } c; c.i = ((u32)u) << 16; return c.f;
}
__device__ __forceinline__ u16 f2b(float f) {
  union { float f; u32 i; } c; c.f = f;
  u32 r = (c.i + 0x7FFFu + ((c.i >> 16) & 1u)) >> 16;
  return (u16)r;
}

// ---------------- embed: feat = node_feat @ W_embed + b; also write out cols 0..79
__global__ void k_embed(const float* __restrict__ nf, const float* __restrict__ We,
                        const float* __restrict__ be, float* __restrict__ feat,
                        float* __restrict__ out) {
  int tid = blockIdx.x * blockDim.x + threadIdx.x;   // NN*64 threads
  int n = tid >> 6, c = tid & 63;
  if (n >= NN) return;
  float acc = be[c];
#pragma unroll
  for (int k = 0; k < IN_DIM; ++k)
    acc += nf[n * IN_DIM + k] * We[k * HID + c];
  feat[n * HID + c] = acc;
  out[n * OUTW + 16 + c] = acc;
  if (c < IN_DIM) out[n * OUTW + c] = nf[n * IN_DIM + c];
}

// ---------------- CSR build over dst
__global__ void k_count(const int* __restrict__ dst, int* __restrict__ counts) {
  int e = blockIdx.x * blockDim.x + threadIdx.x;
  if (e < NE) atomicAdd(&counts[dst[e]], 1);
}

__global__ void k_scan(const int* __restrict__ counts, int* __restrict__ rowptr) {
  __shared__ int sm[1024];
  __shared__ int running;
  if (threadIdx.x == 0) { running = 0; rowptr[0] = 0; }
  __syncthreads();
  for (int base = 0; base < NN; base += 1024) {
    int i = base + threadIdx.x;
    int v = (i < NN) ? counts[i] : 0;
    sm[threadIdx.x] = v;
    __syncthreads();
    for (int off = 1; off < 1024; off <<= 1) {
      int t = (threadIdx.x >= off) ? sm[threadIdx.x - off] : 0;
      __syncthreads();
      sm[threadIdx.x] += t;
      __syncthreads();
    }
    if (i < NN) rowptr[i + 1] = running + sm[threadIdx.x];
    __syncthreads();
    if (threadIdx.x == 0) running += sm[1023];
    __syncthreads();
  }
}

__global__ void k_scatter(const int* __restrict__ dst, const int* __restrict__ rowptr,
                          int* __restrict__ cursor, int* __restrict__ eidx) {
  int e = blockIdx.x * blockDim.x + threadIdx.x;
  if (e >= NE) return;
  int d = dst[e];
  int pos = rowptr[d] + atomicAdd(&cursor[d], 1);
  eidx[pos] = e;
}

// ---------------- permute edges into CSR (dst-grouped) order; edge_feat -> bf16
__global__ void k_permute(const int* __restrict__ eidx, const float* __restrict__ ef,
                          const int* __restrict__ src, const int* __restrict__ dst,
                          u16* __restrict__ efp, int* __restrict__ srcp,
                          int* __restrict__ dstp) {
  int tid = blockIdx.x * blockDim.x + threadIdx.x;   // NE*64 threads
  int i = tid >> 6, c = tid & 63;
  if (i >= NE) return;
  int e = eidx[i];
  efp[i * HID + c] = f2b(ef[e * HID + c]);
  if (c == 0) { srcp[i] = src[e]; dstp[i] = dst[e]; }
}

// ---------------- transpose + bf16-convert W_fij: Wt[n][k] = Wf[k][n]
__global__ void k_prepw(const float* __restrict__ Wf, u16* __restrict__ Wt) {
  int tid = blockIdx.x * blockDim.x + threadIdx.x;   // HID*HD threads
  int n = tid >> 6, k = tid & 63;
  if (n >= HD) return;
  Wt[n * HID + k] = f2b(Wf[k * HD + n]);
}

// ---------------- node projections: fni (+b_att folded), fnj, hn -> bf16
__global__ __launch_bounds__(256) void k_nodeproj(
    const float* __restrict__ feat, const float* __restrict__ Wni,
    const float* __restrict__ Wnj, const float* __restrict__ Wnd,
    const float* __restrict__ batt, u16* __restrict__ fni,
    u16* __restrict__ fnj, u16* __restrict__ hn) {
  __shared__ float hs[8 * HID];
  int n0 = blockIdx.x * 8;
  int c = threadIdx.x;
  for (int i = threadIdx.x; i < 8 * HID; i += 256)
    hs[i] = feat[(n0 + (i >> 6)) * HID + (i & 63)];
  __syncthreads();
  float aI[8] = {0}, aJ[8] = {0}, aN[8] = {0};
  for (int k = 0; k < HID; ++k) {
    float wi = Wni[k * HD + c], wj = Wnj[k * HD + c], wn = Wnd[k * HD + c];
#pragma unroll
    for (int t = 0; t < 8; ++t) {
      float x = hs[t * HID + k];
      aI[t] += x * wi; aJ[t] += x * wj; aN[t] += x * wn;
    }
  }
  float b = batt[c];
#pragma unroll
  for (int t = 0; t < 8; ++t) {
    int n = n0 + t;
    fni[n * HD + c] = f2b(aI[t] + b);
    fnj[n * HD + c] = f2b(aJ[t]);
    hn[n * HD + c]  = f2b(aN[t]);
  }
}

// ---------------- edge logits via MFMA over CSR-ordered edges
// block = 4 waves = 4 heads; 16 edges per tile; grid-stride over 20000 tiles.
// Per wave: B-frags (Wt slice for its head) in registers; A-frags from efp global;
// gather fni[src]+fnj[dst] (own head's 64 cols) -> private f32 LDS slice; epilogue
// reads slice in C-layout, lrelu, dot attn via shfl_xor, writes elog.
__global__ __launch_bounds__(256) void k_edgelogits(
    const u16* __restrict__ efp, const int* __restrict__ srcp,
    const int* __restrict__ dstp, const u16* __restrict__ fni,
    const u16* __restrict__ fnj, const u16* __restrict__ Wt,
    const float* __restrict__ attnL, float* __restrict__ elog) {
  __shared__ float gb[HEADS][16][68];   // per-wave slice, +4 pad
  int h = threadIdx.x >> 6;            // wave = head
  int l = threadIdx.x & 63;
  int q = l >> 4;                      // quad
  int n = l & 15;
  // B fragments: Wt[(h*64 + nt*16 + n)*64 + kk*32 + q*8 .. +7]
  bf16x8 bfr[4][2];
#pragma unroll
  for (int nt = 0; nt < 4; ++nt)
#pragma unroll
    for (int kk = 0; kk < 2; ++kk)
      bfr[nt][kk] = *reinterpret_cast<const bf16x8*>(
          &Wt[(h * 64 + nt * 16 + n) * HID + kk * 32 + q * 8]);
  float at[4];
#pragma unroll
  for (int nt = 0; nt < 4; ++nt) at[nt] = attnL[h * 64 + nt * 16 + n];

  const int NT = NE / 16;  // 20000 tiles
  for (int tile = blockIdx.x; tile < NT; tile += gridDim.x) {
    int e0 = tile * 16;
    // gather phase: own head's 64-col slice for 16 edges
#pragma unroll
    for (int p = 0; p < 4; ++p) {
      int el = p * 4 + q;
      int e = e0 + el;
      int s = srcp[e], d = dstp[e];
      ushort4 a = *reinterpret_cast<const ushort4*>(&fni[(size_t)s * HD + h * 64 + 4 * n]);
      ushort4 b = *reinterpret_cast<const ushort4*>(&fnj[(size_t)d * HD + h * 64 + 4 * n]);
      float4 g;
      g.x = b2f(a.x) + b2f(b.x);
      g.y = b2f(a.y) + b2f(b.y);
      g.z = b2f(a.z) + b2f(b.z);
      g.w = b2f(a.w) + b2f(b.w);
      *reinterpret_cast<float4*>(&gb[h][el][4 * n]) = g;
    }
    // A fragments: rows = 16 edges (m = n), k chunk per quad
    bf16x8 afr0 = *reinterpret_cast<const bf16x8*>(&efp[(size_t)(e0 + n) * HID + q * 8]);
    bf16x8 afr1 = *reinterpret_cast<const bf16x8*>(&efp[(size_t)(e0 + n) * HID + 32 + q * 8]);
    float sumr[4] = {0.f, 0.f, 0.f, 0.f};
#pragma unroll
    for (int nt = 0; nt < 4; ++nt) {
      f32x4 acc = {0.f, 0.f, 0.f, 0.f};
      acc = __builtin_amdgcn_mfma_f32_16x16x32_bf16(afr0, bfr[nt][0], acc, 0, 0, 0);
      acc = __builtin_amdgcn_mfma_f32_16x16x32_bf16(afr1, bfr[nt][1], acc, 0, 0, 0);
#pragma unroll
      for (int r = 0; r < 4; ++r) {
        float v = acc[r] + gb[h][q * 4 + r][nt * 16 + n];
        v = v > 0.f ? v : NEG * v;
        sumr[r] += v * at[nt];
      }
    }
    // reduce over the 16 cols held across lane&15
#pragma unroll
    for (int r = 0; r < 4; ++r) {
      float v = sumr[r];
      v += __shfl_xor(v, 1);
      v += __shfl_xor(v, 2);
      v += __shfl_xor(v, 4);
      v += __shfl_xor(v, 8);
      sumr[r] = v;
    }
    if (n == 0) {
#pragma unroll
      for (int r = 0; r < 4; ++r)
        elog[(e0 + q * 4 + r) * HEADS + h] = sumr[r];
    }
  }
}

// ---------------- per-(node,head) edge softmax over contiguous CSR range
__global__ void k_softmax(const int* __restrict__ rowptr, float* __restrict__ elog) {
  int t = blockIdx.x * blockDim.x + threadIdx.x;
  if (t >= NN * HEADS) return;
  int n = t >> 2, h = t & 3;
  int s0 = rowptr[n], s1 = rowptr[n + 1];
  float m = -1e30f;
  for (int i = s0; i < s1; ++i) m = fmaxf(m, elog[i * HEADS + h]);
  float z = 0.f;
  for (int i = s0; i < s1; ++i) {
    float v = __expf(elog[i * HEADS + h] - m);
    elog[i * HEADS + h] = v;
    z += v;
  }
  if (z > 0.f) {
    float inv = 1.0f / z;
    for (int i = s0; i < s1; ++i) elog[i * HEADS + h] *= inv;
  }
}

// ---------------- aggregation: one wave per node over contiguous CSR range
__global__ __launch_bounds__(256) void k_agg(
    const int* __restrict__ rowptr, const int* __restrict__ srcp,
    const float* __restrict__ elog, const u16* __restrict__ hn,
    float* __restrict__ agg) {
  int n = (blockIdx.x * blockDim.x + threadIdx.x) >> 6;
  int j = threadIdx.x & 63;
  if (n >= NN) return;
  int s0 = rowptr[n], s1 = rowptr[n + 1];
  int h = j >> 4;
  float4 acc = make_float4(0.f, 0.f, 0.f, 0.f);
  for (int i = s0; i < s1; ++i) {
    int s = srcp[i];
    float a = elog[i * HEADS + h];
    ushort4 v = *reinterpret_cast<const ushort4*>(&hn[(size_t)s * HD + 4 * j]);
    acc.x += b2f(v.x) * a; acc.y += b2f(v.y) * a;
    acc.z += b2f(v.z) * a; acc.w += b2f(v.w) * a;
  }
  *reinterpret_cast<float4*>(&agg[n * HD + 4 * j]) = acc;
}

// ---------------- MLP + residual: feat = agg @ W_mlp + b + feat; write out slice
__global__ __launch_bounds__(256) void k_mlp(
    const float* __restrict__ agg, const float* __restrict__ Wm,
    const float* __restrict__ bm, float* __restrict__ feat,
    float* __restrict__ out, int outoff) {
  __shared__ float as_[32 * HD];
  int n0 = blockIdx.x * 32;
  for (int i = threadIdx.x; i < 32 * HD; i += 256) as_[i] = agg[n0 * HD + i];
  __syncthreads();
  int c = threadIdx.x & 63;
  int g = threadIdx.x >> 6;
  float acc[8] = {0};
  for (int k = 0; k < HD; ++k) {
    float wv = Wm[k * HID + c];
#pragma unroll
    for (int t = 0; t < 8; ++t)
      acc[t] += as_[(g * 8 + t) * HD + k] * wv;
  }
  float b = bm[c];
#pragma unroll
  for (int t = 0; t < 8; ++t) {
    int n = n0 + g * 8 + t;
    float v = acc[t] + b + feat[n * HID + c];
    feat[n * HID + c] = v;
    out[n * OUTW + outoff + c] = v;
  }
}

extern "C" void kernel_launch(void* const* d_in, const int* in_sizes, int n_in,
                              void* d_out, int out_size, void* d_ws, size_t ws_size,
                              hipStream_t stream) {
  const float* node_feat = (const float*)d_in[0];
  const float* edge_feat = (const float*)d_in[1];
  const int*   src       = (const int*)d_in[2];
  const int*   dst       = (const int*)d_in[3];
  const float* W_embed   = (const float*)d_in[4];
  const float* b_embed   = (const float*)d_in[5];
  const float* W_ni      = (const float*)d_in[6];
  const float* W_nj      = (const float*)d_in[7];
  const float* W_fij     = (const float*)d_in[8];
  const float* b_att     = (const float*)d_in[9];
  const float* attn      = (const float*)d_in[10];
  const float* W_node    = (const float*)d_in[11];
  const float* W_mlp     = (const float*)d_in[12];
  const float* b_mlp     = (const float*)d_in[13];
  float* out = (float*)d_out;

  // workspace layout
  float* ws   = (float*)d_ws;
  float* feat = ws;                                   // NN*HID f32
  u16*  fni   = (u16*)(feat + (size_t)NN * HID);      // NN*HD bf16
  u16*  fnj   = fni + (size_t)NN * HD;                // NN*HD bf16
  u16*  hn    = fnj + (size_t)NN * HD;                // NN*HD bf16
  u16*  efp   = hn + (size_t)NN * HD;                 // NE*HID bf16
  u16*  Wt    = efp + (size_t)NE * HID;               // HD*HID bf16 (transposed W_fij)
  float* elog = (float*)(Wt + (size_t)HD * HID);      // NE*HEADS f32
  int* counts = (int*)(elog + (size_t)NE * HEADS);    // NN
  int* rowptr = counts + NN;                          // NN+1
  int* cursor = rowptr + NN + 1;                      // NN
  int* eidx   = cursor + NN;                          // NE
  int* srcp   = eidx + NE;                            // NE
  int* dstp   = srcp + NE;                            // NE
  float* aggb = (float*)fni;  // overlay fni+fnj (exactly NN*HD f32); safe: agg
                              // is written after edgelogits consumed fni/fnj.

  hipMemsetAsync(counts, 0, sizeof(int) * NN, stream);
  hipMemsetAsync(cursor, 0, sizeof(int) * NN, stream);

  k_embed<<<(NN * 64) / 256, 256, 0, stream>>>(node_feat, W_embed, b_embed, feat, out);
  k_count<<<NE / 256, 256, 0, stream>>>(dst, counts);
  k_scan<<<1, 1024, 0, stream>>>(counts, rowptr);
  k_scatter<<<NE / 256, 256, 0, stream>>>(dst, rowptr, cursor, eidx);
  k_permute<<<((size_t)NE * 64) / 256, 256, 0, stream>>>(eidx, edge_feat, src, dst,
                                                         efp, srcp, dstp);

  for (int L = 0; L < 2; ++L) {
    const float* WniL = W_ni + (size_t)L * HID * HD;
    const float* WnjL = W_nj + (size_t)L * HID * HD;
    const float* WfL  = W_fij + (size_t)L * HID * HD;
    const float* WndL = W_node + (size_t)L * HID * HD;
    const float* battL = b_att + (size_t)L * HD;
    const float* attnL = attn + (size_t)L * HEADS * HID;
    const float* WmL  = W_mlp + (size_t)L * HD * HID;
    const float* bmL  = b_mlp + (size_t)L * HID;

    k_prepw<<<(HID * HD) / 256, 256, 0, stream>>>(WfL, Wt);
    k_nodeproj<<<NN / 8, 256, 0, stream>>>(feat, WniL, WnjL, WndL, battL, fni, fnj, hn);
    k_edgelogits<<<1280, 256, 0, stream>>>(efp, srcp, dstp, fni, fnj, Wt, attnL, elog);
    k_softmax<<<(NN * HEADS + 255) / 256, 256, 0, stream>>>(rowptr, elog);
    k_agg<<<(NN * 64) / 256, 256, 0, stream>>>(rowptr, srcp, elog, hn, aggb);
    k_mlp<<<NN / 32, 256, 0, stream>>>(aggb, WmL, bmL, feat, out, 80 + L * 64);
  }
}

// Round 4
// 596.015 us; speedup vs baseline: 1.9067x; 1.1557x over previous
//
#include <hip/hip_runtime.h>
#include <math.h>

#define NN 20000
#define NE 320000
#define IN_DIM 16
#define HID 64
#define HEADS 4
#define HD 256          // HEADS*HID
#define OUTW 208        // 16 + 3*64
#define NEG 0.2f

typedef unsigned short u16;
typedef unsigned int u32;
typedef __attribute__((ext_vector_type(8))) short bf16x8;   // MFMA A/B frag
typedef __attribute__((ext_vector_type(4))) float f32x4;    // MFMA C/D frag

__device__ __forceinline__ float b2f(u16 u) {
  union { u32 i; float f; } c; c.i = ((u32)u) << 16; return c.f;
}
__device__ __forceinline__ u16 f2b(float f) {
  union { float f; u32 i; } c; c.f = f;
  u32 r = (c.i + 0x7FFFu + ((c.i >> 16) & 1u)) >> 16;
  return (u16)r;
}

// ---------------- embed: feat = node_feat @ W_embed + b; also write out cols 0..79
__global__ void k_embed(const float* __restrict__ nf, const float* __restrict__ We,
                        const float* __restrict__ be, float* __restrict__ feat,
                        float* __restrict__ out) {
  int tid = blockIdx.x * blockDim.x + threadIdx.x;   // NN*64 threads
  int n = tid >> 6, c = tid & 63;
  if (n >= NN) return;
  float acc = be[c];
#pragma unroll
  for (int k = 0; k < IN_DIM; ++k)
    acc += nf[n * IN_DIM + k] * We[k * HID + c];
  feat[n * HID + c] = acc;
  out[n * OUTW + 16 + c] = acc;
  if (c < IN_DIM) out[n * OUTW + c] = nf[n * IN_DIM + c];
}

// ---------------- CSR build over dst
__global__ void k_count(const int* __restrict__ dst, int* __restrict__ counts) {
  int e = blockIdx.x * blockDim.x + threadIdx.x;
  if (e < NE) atomicAdd(&counts[dst[e]], 1);
}

__global__ void k_scan(const int* __restrict__ counts, int* __restrict__ rowptr) {
  __shared__ int sm[1024];
  __shared__ int running;
  if (threadIdx.x == 0) { running = 0; rowptr[0] = 0; }
  __syncthreads();
  for (int base = 0; base < NN; base += 1024) {
    int i = base + threadIdx.x;
    int v = (i < NN) ? counts[i] : 0;
    sm[threadIdx.x] = v;
    __syncthreads();
    for (int off = 1; off < 1024; off <<= 1) {
      int t = (threadIdx.x >= off) ? sm[threadIdx.x - off] : 0;
      __syncthreads();
      sm[threadIdx.x] += t;
      __syncthreads();
    }
    if (i < NN) rowptr[i + 1] = running + sm[threadIdx.x];
    __syncthreads();
    if (threadIdx.x == 0) running += sm[1023];
    __syncthreads();
  }
}

// scatter: record CSR slot per edge, and src permuted into CSR order
__global__ void k_scatter(const int* __restrict__ dst, const int* __restrict__ src,
                          const int* __restrict__ rowptr, int* __restrict__ cursor,
                          int* __restrict__ posArr, int* __restrict__ srcp) {
  int e = blockIdx.x * blockDim.x + threadIdx.x;
  if (e >= NE) return;
  int d = dst[e];
  int pos = rowptr[d] + atomicAdd(&cursor[d], 1);
  posArr[e] = pos;
  srcp[pos] = src[e];
}

// ---------------- coalesced f32 -> bf16 convert of edge_feat (original order)
__global__ void k_convert(const float* __restrict__ ef, u16* __restrict__ efb) {
  int t = blockIdx.x * blockDim.x + threadIdx.x;   // NE*HID/4 threads
  float4 v = *reinterpret_cast<const float4*>(&ef[(size_t)t * 4]);
  ushort4 o;
  o.x = f2b(v.x); o.y = f2b(v.y); o.z = f2b(v.z); o.w = f2b(v.w);
  *reinterpret_cast<ushort4*>(&efb[(size_t)t * 4]) = o;
}

// ---------------- transpose + bf16-convert W_fij: Wt[n][k] = Wf[k][n]
__global__ void k_prepw(const float* __restrict__ Wf, u16* __restrict__ Wt) {
  int tid = blockIdx.x * blockDim.x + threadIdx.x;   // HID*HD threads
  int n = tid >> 6, k = tid & 63;
  if (n >= HD) return;
  Wt[n * HID + k] = f2b(Wf[k * HD + n]);
}

// ---------------- node projections: fni (+b_att folded), fnj, hn -> bf16
__global__ __launch_bounds__(256) void k_nodeproj(
    const float* __restrict__ feat, const float* __restrict__ Wni,
    const float* __restrict__ Wnj, const float* __restrict__ Wnd,
    const float* __restrict__ batt, u16* __restrict__ fni,
    u16* __restrict__ fnj, u16* __restrict__ hn) {
  __shared__ float hs[8 * HID];
  int n0 = blockIdx.x * 8;
  int c = threadIdx.x;
  for (int i = threadIdx.x; i < 8 * HID; i += 256)
    hs[i] = feat[(n0 + (i >> 6)) * HID + (i & 63)];
  __syncthreads();
  float aI[8] = {0}, aJ[8] = {0}, aN[8] = {0};
  for (int k = 0; k < HID; ++k) {
    float wi = Wni[k * HD + c], wj = Wnj[k * HD + c], wn = Wnd[k * HD + c];
#pragma unroll
    for (int t = 0; t < 8; ++t) {
      float x = hs[t * HID + k];
      aI[t] += x * wi; aJ[t] += x * wj; aN[t] += x * wn;
    }
  }
  float b = batt[c];
#pragma unroll
  for (int t = 0; t < 8; ++t) {
    int n = n0 + t;
    fni[n * HD + c] = f2b(aI[t] + b);
    fnj[n * HD + c] = f2b(aJ[t]);
    hn[n * HD + c]  = f2b(aN[t]);
  }
}

// ---------------- edge logits via MFMA, original edge order, scatter-write elog
__global__ __launch_bounds__(256) void k_edgelogits(
    const u16* __restrict__ efb, const int* __restrict__ src,
    const int* __restrict__ dst, const int* __restrict__ posArr,
    const u16* __restrict__ fni, const u16* __restrict__ fnj,
    const u16* __restrict__ Wt, const float* __restrict__ attnL,
    float* __restrict__ elog) {
  __shared__ float gb[HEADS][16][68];   // per-wave slice, +4 pad
  int h = threadIdx.x >> 6;            // wave = head
  int l = threadIdx.x & 63;
  int q = l >> 4;                      // quad
  int n = l & 15;
  bf16x8 bfr[4][2];
#pragma unroll
  for (int nt = 0; nt < 4; ++nt)
#pragma unroll
    for (int kk = 0; kk < 2; ++kk)
      bfr[nt][kk] = *reinterpret_cast<const bf16x8*>(
          &Wt[(h * 64 + nt * 16 + n) * HID + kk * 32 + q * 8]);
  float at[4];
#pragma unroll
  for (int nt = 0; nt < 4; ++nt) at[nt] = attnL[h * 64 + nt * 16 + n];

  const int NT = NE / 16;  // 20000 tiles
  for (int tile = blockIdx.x; tile < NT; tile += gridDim.x) {
    int e0 = tile * 16;
    // CSR slot for the 4 edges this lane's quad will write in the epilogue
    int pe[4];
#pragma unroll
    for (int r = 0; r < 4; ++r) pe[r] = posArr[e0 + q * 4 + r];
    // gather phase: own head's 64-col slice for 16 edges
#pragma unroll
    for (int p = 0; p < 4; ++p) {
      int el = p * 4 + q;
      int e = e0 + el;
      int s = src[e], d = dst[e];
      ushort4 a = *reinterpret_cast<const ushort4*>(&fni[(size_t)s * HD + h * 64 + 4 * n]);
      ushort4 b = *reinterpret_cast<const ushort4*>(&fnj[(size_t)d * HD + h * 64 + 4 * n]);
      float4 g;
      g.x = b2f(a.x) + b2f(b.x);
      g.y = b2f(a.y) + b2f(b.y);
      g.z = b2f(a.z) + b2f(b.z);
      g.w = b2f(a.w) + b2f(b.w);
      *reinterpret_cast<float4*>(&gb[h][el][4 * n]) = g;
    }
    // A fragments: rows = 16 consecutive edges, k chunk per quad
    bf16x8 afr0 = *reinterpret_cast<const bf16x8*>(&efb[(size_t)(e0 + n) * HID + q * 8]);
    bf16x8 afr1 = *reinterpret_cast<const bf16x8*>(&efb[(size_t)(e0 + n) * HID + 32 + q * 8]);
    float sumr[4] = {0.f, 0.f, 0.f, 0.f};
#pragma unroll
    for (int nt = 0; nt < 4; ++nt) {
      f32x4 acc = {0.f, 0.f, 0.f, 0.f};
      acc = __builtin_amdgcn_mfma_f32_16x16x32_bf16(afr0, bfr[nt][0], acc, 0, 0, 0);
      acc = __builtin_amdgcn_mfma_f32_16x16x32_bf16(afr1, bfr[nt][1], acc, 0, 0, 0);
#pragma unroll
      for (int r = 0; r < 4; ++r) {
        float v = acc[r] + gb[h][q * 4 + r][nt * 16 + n];
        v = v > 0.f ? v : NEG * v;
        sumr[r] += v * at[nt];
      }
    }
#pragma unroll
    for (int r = 0; r < 4; ++r) {
      float v = sumr[r];
      v += __shfl_xor(v, 1);
      v += __shfl_xor(v, 2);
      v += __shfl_xor(v, 4);
      v += __shfl_xor(v, 8);
      sumr[r] = v;
    }
    if (n == 0) {
#pragma unroll
      for (int r = 0; r < 4; ++r)
        elog[(size_t)pe[r] * HEADS + h] = sumr[r];
    }
  }
}

// ---------------- per-(node,head) softmax stats: m and 1/z (elog read-only)
__global__ void k_mz(const int* __restrict__ rowptr, const float* __restrict__ elog,
                     float* __restrict__ mz) {
  int t = blockIdx.x * blockDim.x + threadIdx.x;
  if (t >= NN * HEADS) return;
  int n = t >> 2, h = t & 3;
  int s0 = rowptr[n], s1 = rowptr[n + 1];
  float m = -1e30f;
  for (int i = s0; i < s1; ++i) m = fmaxf(m, elog[i * HEADS + h]);
  float z = 0.f;
  for (int i = s0; i < s1; ++i) z += __expf(elog[i * HEADS + h] - m);
  mz[n * 8 + h] = m;
  mz[n * 8 + 4 + h] = (z > 0.f) ? 1.0f / z : 0.f;
}

// ---------------- aggregation: one wave per node, unroll x4, softmax applied on the fly
__global__ __launch_bounds__(256) void k_agg(
    const int* __restrict__ rowptr, const int* __restrict__ srcp,
    const float* __restrict__ elog, const float* __restrict__ mz,
    const u16* __restrict__ hn, float* __restrict__ agg) {
  int n = (blockIdx.x * blockDim.x + threadIdx.x) >> 6;
  int j = threadIdx.x & 63;
  if (n >= NN) return;
  int s0 = rowptr[n], s1 = rowptr[n + 1];
  int h = j >> 4;
  float m = mz[n * 8 + h], invz = mz[n * 8 + 4 + h];
  float4 a0 = make_float4(0, 0, 0, 0), a1 = a0, a2 = a0, a3 = a0;
  int i = s0;
  for (; i + 4 <= s1; i += 4) {
    int sA = srcp[i], sB = srcp[i + 1], sC = srcp[i + 2], sD = srcp[i + 3];
    float wA = __expf(elog[(i + 0) * HEADS + h] - m) * invz;
    float wB = __expf(elog[(i + 1) * HEADS + h] - m) * invz;
    float wC = __expf(elog[(i + 2) * HEADS + h] - m) * invz;
    float wD = __expf(elog[(i + 3) * HEADS + h] - m) * invz;
    ushort4 vA = *reinterpret_cast<const ushort4*>(&hn[(size_t)sA * HD + 4 * j]);
    ushort4 vB = *reinterpret_cast<const ushort4*>(&hn[(size_t)sB * HD + 4 * j]);
    ushort4 vC = *reinterpret_cast<const ushort4*>(&hn[(size_t)sC * HD + 4 * j]);
    ushort4 vD = *reinterpret_cast<const ushort4*>(&hn[(size_t)sD * HD + 4 * j]);
    a0.x += b2f(vA.x) * wA; a0.y += b2f(vA.y) * wA; a0.z += b2f(vA.z) * wA; a0.w += b2f(vA.w) * wA;
    a1.x += b2f(vB.x) * wB; a1.y += b2f(vB.y) * wB; a1.z += b2f(vB.z) * wB; a1.w += b2f(vB.w) * wB;
    a2.x += b2f(vC.x) * wC; a2.y += b2f(vC.y) * wC; a2.z += b2f(vC.z) * wC; a2.w += b2f(vC.w) * wC;
    a3.x += b2f(vD.x) * wD; a3.y += b2f(vD.y) * wD; a3.z += b2f(vD.z) * wD; a3.w += b2f(vD.w) * wD;
  }
  for (; i < s1; ++i) {
    int s = srcp[i];
    float w = __expf(elog[i * HEADS + h] - m) * invz;
    ushort4 v = *reinterpret_cast<const ushort4*>(&hn[(size_t)s * HD + 4 * j]);
    a0.x += b2f(v.x) * w; a0.y += b2f(v.y) * w; a0.z += b2f(v.z) * w; a0.w += b2f(v.w) * w;
  }
  float4 acc;
  acc.x = (a0.x + a1.x) + (a2.x + a3.x);
  acc.y = (a0.y + a1.y) + (a2.y + a3.y);
  acc.z = (a0.z + a1.z) + (a2.z + a3.z);
  acc.w = (a0.w + a1.w) + (a2.w + a3.w);
  *reinterpret_cast<float4*>(&agg[(size_t)n * HD + 4 * j]) = acc;
}

// ---------------- MLP + residual: feat = agg @ W_mlp + b + feat; write out slice
__global__ __launch_bounds__(256) void k_mlp(
    const float* __restrict__ agg, const float* __restrict__ Wm,
    const float* __restrict__ bm, float* __restrict__ feat,
    float* __restrict__ out, int outoff) {
  __shared__ float as_[32 * HD];
  int n0 = blockIdx.x * 32;
  for (int i = threadIdx.x; i < 32 * HD; i += 256) as_[i] = agg[(size_t)n0 * HD + i];
  __syncthreads();
  int c = threadIdx.x & 63;
  int g = threadIdx.x >> 6;
  float acc[8] = {0};
  for (int k = 0; k < HD; ++k) {
    float wv = Wm[k * HID + c];
#pragma unroll
    for (int t = 0; t < 8; ++t)
      acc[t] += as_[(g * 8 + t) * HD + k] * wv;
  }
  float b = bm[c];
#pragma unroll
  for (int t = 0; t < 8; ++t) {
    int n = n0 + g * 8 + t;
    float v = acc[t] + b + feat[n * HID + c];
    feat[n * HID + c] = v;
    out[n * OUTW + outoff + c] = v;
  }
}

extern "C" void kernel_launch(void* const* d_in, const int* in_sizes, int n_in,
                              void* d_out, int out_size, void* d_ws, size_t ws_size,
                              hipStream_t stream) {
  const float* node_feat = (const float*)d_in[0];
  const float* edge_feat = (const float*)d_in[1];
  const int*   src       = (const int*)d_in[2];
  const int*   dst       = (const int*)d_in[3];
  const float* W_embed   = (const float*)d_in[4];
  const float* b_embed   = (const float*)d_in[5];
  const float* W_ni      = (const float*)d_in[6];
  const float* W_nj      = (const float*)d_in[7];
  const float* W_fij     = (const float*)d_in[8];
  const float* b_att     = (const float*)d_in[9];
  const float* attn      = (const float*)d_in[10];
  const float* W_node    = (const float*)d_in[11];
  const float* W_mlp     = (const float*)d_in[12];
  const float* b_mlp     = (const float*)d_in[13];
  float* out = (float*)d_out;

  // workspace layout
  float* ws   = (float*)d_ws;
  float* feat = ws;                                   // NN*HID f32
  u16*  fni   = (u16*)(feat + (size_t)NN * HID);      // NN*HD bf16
  u16*  fnj   = fni + (size_t)NN * HD;                // NN*HD bf16
  u16*  hn    = fnj + (size_t)NN * HD;                // NN*HD bf16
  u16*  efb   = hn + (size_t)NN * HD;                 // NE*HID bf16 (original order)
  u16*  Wt    = efb + (size_t)NE * HID;               // HD*HID bf16
  float* elog = (float*)(Wt + (size_t)HD * HID);      // NE*HEADS f32 (CSR order)
  float* mz   = elog + (size_t)NE * HEADS;            // NN*8 f32
  int* counts = (int*)(mz + (size_t)NN * 8);          // NN
  int* rowptr = counts + NN;                          // NN+1
  int* cursor = rowptr + NN + 1;                      // NN
  int* posArr = cursor + NN;                          // NE
  int* srcp   = posArr + NE;                          // NE
  float* aggb = (float*)fni;  // overlay fni+fnj; safe: written after edgelogits.

  hipMemsetAsync(counts, 0, sizeof(int) * NN, stream);
  hipMemsetAsync(cursor, 0, sizeof(int) * NN, stream);

  k_embed<<<(NN * 64) / 256, 256, 0, stream>>>(node_feat, W_embed, b_embed, feat, out);
  k_count<<<NE / 256, 256, 0, stream>>>(dst, counts);
  k_scan<<<1, 1024, 0, stream>>>(counts, rowptr);
  k_scatter<<<NE / 256, 256, 0, stream>>>(dst, src, rowptr, cursor, posArr, srcp);
  k_convert<<<(NE * HID / 4) / 256, 256, 0, stream>>>(edge_feat, efb);

  for (int L = 0; L < 2; ++L) {
    const float* WniL = W_ni + (size_t)L * HID * HD;
    const float* WnjL = W_nj + (size_t)L * HID * HD;
    const float* WfL  = W_fij + (size_t)L * HID * HD;
    const float* WndL = W_node + (size_t)L * HID * HD;
    const float* battL = b_att + (size_t)L * HD;
    const float* attnL = attn + (size_t)L * HEADS * HID;
    const float* WmL  = W_mlp + (size_t)L * HD * HID;
    const float* bmL  = b_mlp + (size_t)L * HID;

    k_prepw<<<(HID * HD) / 256, 256, 0, stream>>>(WfL, Wt);
    k_nodeproj<<<NN / 8, 256, 0, stream>>>(feat, WniL, WnjL, WndL, battL, fni, fnj, hn);
    k_edgelogits<<<1280, 256, 0, stream>>>(efb, src, dst, posArr, fni, fnj, Wt, attnL, elog);
    k_mz<<<(NN * HEADS + 255) / 256, 256, 0, stream>>>(rowptr, elog, mz);
    k_agg<<<(NN * 64) / 256, 256, 0, stream>>>(rowptr, srcp, elog, mz, hn, aggb);
    k_mlp<<<NN / 32, 256, 0, stream>>>(aggb, WmL, bmL, feat, out, 80 + L * 64);
  }
}

// Round 5
// 585.290 us; speedup vs baseline: 1.9416x; 1.0183x over previous
//
#include <hip/hip_runtime.h>
#include <math.h>

#define NN 20000
#define NE 320000
#define IN_DIM 16
#define HID 64
#define HEADS 4
#define HD 256          // HEADS*HID
#define OUTW 208        // 16 + 3*64
#define NEG 0.2f

typedef unsigned short u16;
typedef unsigned int u32;
typedef __attribute__((ext_vector_type(8))) short bf16x8;   // MFMA A/B frag
typedef __attribute__((ext_vector_type(4))) float f32x4;    // MFMA C/D frag

__device__ __forceinline__ float b2f(u16 u) {
  union { u32 i; float f; } c; c.i = ((u32)u) << 16; return c.f;
}
__device__ __forceinline__ u16 f2b(float f) {
  union { float f; u32 i; } c; c.f = f;
  u32 r = (c.i + 0x7FFFu + ((c.i >> 16) & 1u)) >> 16;
  return (u16)r;
}

// ---------------- embed: feat = node_feat @ W_embed + b; also write out cols 0..79
__global__ void k_embed(const float* __restrict__ nf, const float* __restrict__ We,
                        const float* __restrict__ be, float* __restrict__ feat,
                        float* __restrict__ out) {
  int tid = blockIdx.x * blockDim.x + threadIdx.x;   // NN*64 threads
  int n = tid >> 6, c = tid & 63;
  if (n >= NN) return;
  float acc = be[c];
#pragma unroll
  for (int k = 0; k < IN_DIM; ++k)
    acc += nf[n * IN_DIM + k] * We[k * HID + c];
  feat[n * HID + c] = acc;
  out[n * OUTW + 16 + c] = acc;
  if (c < IN_DIM) out[n * OUTW + c] = nf[n * IN_DIM + c];
}

// ---------------- CSR build over dst
__global__ void k_count(const int* __restrict__ dst, int* __restrict__ counts) {
  int e = blockIdx.x * blockDim.x + threadIdx.x;
  if (e < NE) atomicAdd(&counts[dst[e]], 1);
}

__global__ void k_scan(const int* __restrict__ counts, int* __restrict__ rowptr) {
  __shared__ int sm[1024];
  __shared__ int running;
  if (threadIdx.x == 0) { running = 0; rowptr[0] = 0; }
  __syncthreads();
  for (int base = 0; base < NN; base += 1024) {
    int i = base + threadIdx.x;
    int v = (i < NN) ? counts[i] : 0;
    sm[threadIdx.x] = v;
    __syncthreads();
    for (int off = 1; off < 1024; off <<= 1) {
      int t = (threadIdx.x >= off) ? sm[threadIdx.x - off] : 0;
      __syncthreads();
      sm[threadIdx.x] += t;
      __syncthreads();
    }
    if (i < NN) rowptr[i + 1] = running + sm[threadIdx.x];
    __syncthreads();
    if (threadIdx.x == 0) running += sm[1023];
    __syncthreads();
  }
}

// scatter: eidx (CSR slot -> original edge), src/dst permuted into CSR order
__global__ void k_scatter(const int* __restrict__ dst, const int* __restrict__ src,
                          const int* __restrict__ rowptr, int* __restrict__ cursor,
                          int* __restrict__ eidx, int* __restrict__ srcp,
                          int* __restrict__ dstp) {
  int e = blockIdx.x * blockDim.x + threadIdx.x;
  if (e >= NE) return;
  int d = dst[e];
  int pos = rowptr[d] + atomicAdd(&cursor[d], 1);
  eidx[pos] = e;
  srcp[pos] = src[e];
  dstp[pos] = d;
}

// ---------------- coalesced f32 -> bf16 convert of edge_feat (original order)
__global__ void k_convert(const float* __restrict__ ef, u16* __restrict__ efb) {
  int t = blockIdx.x * blockDim.x + threadIdx.x;   // NE*HID/4 threads
  float4 v = *reinterpret_cast<const float4*>(&ef[(size_t)t * 4]);
  ushort4 o;
  o.x = f2b(v.x); o.y = f2b(v.y); o.z = f2b(v.z); o.w = f2b(v.w);
  *reinterpret_cast<ushort4*>(&efb[(size_t)t * 4]) = o;
}

// ---------------- transpose + bf16-convert W_fij: Wt[n][k] = Wf[k][n]
__global__ void k_prepw(const float* __restrict__ Wf, u16* __restrict__ Wt) {
  int tid = blockIdx.x * blockDim.x + threadIdx.x;   // HID*HD threads
  int n = tid >> 6, k = tid & 63;
  if (n >= HD) return;
  Wt[n * HID + k] = f2b(Wf[k * HD + n]);
}

// ---------------- node projections: fni (+b_att folded), fnj, hn -> bf16
__global__ __launch_bounds__(256) void k_nodeproj(
    const float* __restrict__ feat, const float* __restrict__ Wni,
    const float* __restrict__ Wnj, const float* __restrict__ Wnd,
    const float* __restrict__ batt, u16* __restrict__ fni,
    u16* __restrict__ fnj, u16* __restrict__ hn) {
  __shared__ float hs[8 * HID];
  int n0 = blockIdx.x * 8;
  int c = threadIdx.x;
  for (int i = threadIdx.x; i < 8 * HID; i += 256)
    hs[i] = feat[(n0 + (i >> 6)) * HID + (i & 63)];
  __syncthreads();
  float aI[8] = {0}, aJ[8] = {0}, aN[8] = {0};
  for (int k = 0; k < HID; ++k) {
    float wi = Wni[k * HD + c], wj = Wnj[k * HD + c], wn = Wnd[k * HD + c];
#pragma unroll
    for (int t = 0; t < 8; ++t) {
      float x = hs[t * HID + k];
      aI[t] += x * wi; aJ[t] += x * wj; aN[t] += x * wn;
    }
  }
  float b = batt[c];
#pragma unroll
  for (int t = 0; t < 8; ++t) {
    int n = n0 + t;
    fni[n * HD + c] = f2b(aI[t] + b);
    fnj[n * HD + c] = f2b(aJ[t]);
    hn[n * HD + c]  = f2b(aN[t]);
  }
}

// ---------------- edge logits via MFMA over CSR slots
// A-frags gathered via eidx from efb (original order); fnj[dstp] dst-grouped;
// elog written sequentially in CSR order.
__global__ __launch_bounds__(256) void k_edgelogits(
    const u16* __restrict__ efb, const int* __restrict__ eidx,
    const int* __restrict__ srcp, const int* __restrict__ dstp,
    const u16* __restrict__ fni, const u16* __restrict__ fnj,
    const u16* __restrict__ Wt, const float* __restrict__ attnL,
    float* __restrict__ elog) {
  __shared__ float gb[HEADS][16][68];   // per-wave slice, +4 pad
  int h = threadIdx.x >> 6;            // wave = head
  int l = threadIdx.x & 63;
  int q = l >> 4;                      // quad
  int n = l & 15;
  bf16x8 bfr[4][2];
#pragma unroll
  for (int nt = 0; nt < 4; ++nt)
#pragma unroll
    for (int kk = 0; kk < 2; ++kk)
      bfr[nt][kk] = *reinterpret_cast<const bf16x8*>(
          &Wt[(h * 64 + nt * 16 + n) * HID + kk * 32 + q * 8]);
  float at[4];
#pragma unroll
  for (int nt = 0; nt < 4; ++nt) at[nt] = attnL[h * 64 + nt * 16 + n];

  const int NT = NE / 16;  // 20000 tiles
  for (int tile = blockIdx.x; tile < NT; tile += gridDim.x) {
    int i0 = tile * 16;
    // A fragment rows: CSR slot i0+n -> original edge eidx[i0+n]
    int er = eidx[i0 + n];
    bf16x8 afr0 = *reinterpret_cast<const bf16x8*>(&efb[(size_t)er * HID + q * 8]);
    bf16x8 afr1 = *reinterpret_cast<const bf16x8*>(&efb[(size_t)er * HID + 32 + q * 8]);
    // gather phase: own head's 64-col slice for 16 CSR slots
#pragma unroll
    for (int p = 0; p < 4; ++p) {
      int el = p * 4 + q;
      int i = i0 + el;
      int s = srcp[i], d = dstp[i];
      ushort4 a = *reinterpret_cast<const ushort4*>(&fni[(size_t)s * HD + h * 64 + 4 * n]);
      ushort4 b = *reinterpret_cast<const ushort4*>(&fnj[(size_t)d * HD + h * 64 + 4 * n]);
      float4 g;
      g.x = b2f(a.x) + b2f(b.x);
      g.y = b2f(a.y) + b2f(b.y);
      g.z = b2f(a.z) + b2f(b.z);
      g.w = b2f(a.w) + b2f(b.w);
      *reinterpret_cast<float4*>(&gb[h][el][4 * n]) = g;
    }
    float sumr[4] = {0.f, 0.f, 0.f, 0.f};
#pragma unroll
    for (int nt = 0; nt < 4; ++nt) {
      f32x4 acc = {0.f, 0.f, 0.f, 0.f};
      acc = __builtin_amdgcn_mfma_f32_16x16x32_bf16(afr0, bfr[nt][0], acc, 0, 0, 0);
      acc = __builtin_amdgcn_mfma_f32_16x16x32_bf16(afr1, bfr[nt][1], acc, 0, 0, 0);
#pragma unroll
      for (int r = 0; r < 4; ++r) {
        float v = acc[r] + gb[h][q * 4 + r][nt * 16 + n];
        v = v > 0.f ? v : NEG * v;
        sumr[r] += v * at[nt];
      }
    }
#pragma unroll
    for (int r = 0; r < 4; ++r) {
      float v = sumr[r];
      v += __shfl_xor(v, 1);
      v += __shfl_xor(v, 2);
      v += __shfl_xor(v, 4);
      v += __shfl_xor(v, 8);
      sumr[r] = v;
    }
    if (n == 0) {
#pragma unroll
      for (int r = 0; r < 4; ++r)
        elog[(size_t)(i0 + q * 4 + r) * HEADS + h] = sumr[r];
    }
  }
}

// ---------------- per-(node,head) softmax stats: m and 1/z (elog read-only)
__global__ void k_mz(const int* __restrict__ rowptr, const float* __restrict__ elog,
                     float* __restrict__ mz) {
  int t = blockIdx.x * blockDim.x + threadIdx.x;
  if (t >= NN * HEADS) return;
  int n = t >> 2, h = t & 3;
  int s0 = rowptr[n], s1 = rowptr[n + 1];
  float m = -1e30f;
  for (int i = s0; i < s1; ++i) m = fmaxf(m, elog[i * HEADS + h]);
  float z = 0.f;
  for (int i = s0; i < s1; ++i) z += __expf(elog[i * HEADS + h] - m);
  mz[n * 8 + h] = m;
  mz[n * 8 + 4 + h] = (z > 0.f) ? 1.0f / z : 0.f;
}

// ---------------- aggregation: one wave per node, unroll x8, softmax on the fly
__global__ __launch_bounds__(256) void k_agg(
    const int* __restrict__ rowptr, const int* __restrict__ srcp,
    const float* __restrict__ elog, const float* __restrict__ mz,
    const u16* __restrict__ hn, float* __restrict__ agg) {
  int n = (blockIdx.x * blockDim.x + threadIdx.x) >> 6;
  int j = threadIdx.x & 63;
  if (n >= NN) return;
  int s0 = rowptr[n], s1 = rowptr[n + 1];
  int h = j >> 4;
  float m = mz[n * 8 + h], invz = mz[n * 8 + 4 + h];
  float4 ac[8];
#pragma unroll
  for (int t = 0; t < 8; ++t) ac[t] = make_float4(0, 0, 0, 0);
  int i = s0;
  for (; i + 8 <= s1; i += 8) {
    int sv[8]; float wv[8]; ushort4 vv[8];
#pragma unroll
    for (int t = 0; t < 8; ++t) sv[t] = srcp[i + t];
#pragma unroll
    for (int t = 0; t < 8; ++t) wv[t] = __expf(elog[(i + t) * HEADS + h] - m) * invz;
#pragma unroll
    for (int t = 0; t < 8; ++t)
      vv[t] = *reinterpret_cast<const ushort4*>(&hn[(size_t)sv[t] * HD + 4 * j]);
#pragma unroll
    for (int t = 0; t < 8; ++t) {
      ac[t].x += b2f(vv[t].x) * wv[t]; ac[t].y += b2f(vv[t].y) * wv[t];
      ac[t].z += b2f(vv[t].z) * wv[t]; ac[t].w += b2f(vv[t].w) * wv[t];
    }
  }
  for (; i < s1; ++i) {
    int s = srcp[i];
    float w = __expf(elog[i * HEADS + h] - m) * invz;
    ushort4 v = *reinterpret_cast<const ushort4*>(&hn[(size_t)s * HD + 4 * j]);
    ac[0].x += b2f(v.x) * w; ac[0].y += b2f(v.y) * w;
    ac[0].z += b2f(v.z) * w; ac[0].w += b2f(v.w) * w;
  }
  float4 acc;
  acc.x = ((ac[0].x + ac[1].x) + (ac[2].x + ac[3].x)) + ((ac[4].x + ac[5].x) + (ac[6].x + ac[7].x));
  acc.y = ((ac[0].y + ac[1].y) + (ac[2].y + ac[3].y)) + ((ac[4].y + ac[5].y) + (ac[6].y + ac[7].y));
  acc.z = ((ac[0].z + ac[1].z) + (ac[2].z + ac[3].z)) + ((ac[4].z + ac[5].z) + (ac[6].z + ac[7].z));
  acc.w = ((ac[0].w + ac[1].w) + (ac[2].w + ac[3].w)) + ((ac[4].w + ac[5].w) + (ac[6].w + ac[7].w));
  *reinterpret_cast<float4*>(&agg[(size_t)n * HD + 4 * j]) = acc;
}

// ---------------- MLP + residual: feat = agg @ W_mlp + b + feat; write out slice
__global__ __launch_bounds__(256) void k_mlp(
    const float* __restrict__ agg, const float* __restrict__ Wm,
    const float* __restrict__ bm, float* __restrict__ feat,
    float* __restrict__ out, int outoff) {
  __shared__ float as_[32 * HD];
  int n0 = blockIdx.x * 32;
  for (int i = threadIdx.x; i < 32 * HD; i += 256) as_[i] = agg[(size_t)n0 * HD + i];
  __syncthreads();
  int c = threadIdx.x & 63;
  int g = threadIdx.x >> 6;
  float acc[8] = {0};
  for (int k = 0; k < HD; ++k) {
    float wv = Wm[k * HID + c];
#pragma unroll
    for (int t = 0; t < 8; ++t)
      acc[t] += as_[(g * 8 + t) * HD + k] * wv;
  }
  float b = bm[c];
#pragma unroll
  for (int t = 0; t < 8; ++t) {
    int n = n0 + g * 8 + t;
    float v = acc[t] + b + feat[n * HID + c];
    feat[n * HID + c] = v;
    out[n * OUTW + outoff + c] = v;
  }
}

extern "C" void kernel_launch(void* const* d_in, const int* in_sizes, int n_in,
                              void* d_out, int out_size, void* d_ws, size_t ws_size,
                              hipStream_t stream) {
  const float* node_feat = (const float*)d_in[0];
  const float* edge_feat = (const float*)d_in[1];
  const int*   src       = (const int*)d_in[2];
  const int*   dst       = (const int*)d_in[3];
  const float* W_embed   = (const float*)d_in[4];
  const float* b_embed   = (const float*)d_in[5];
  const float* W_ni      = (const float*)d_in[6];
  const float* W_nj      = (const float*)d_in[7];
  const float* W_fij     = (const float*)d_in[8];
  const float* b_att     = (const float*)d_in[9];
  const float* attn      = (const float*)d_in[10];
  const float* W_node    = (const float*)d_in[11];
  const float* W_mlp     = (const float*)d_in[12];
  const float* b_mlp     = (const float*)d_in[13];
  float* out = (float*)d_out;

  // workspace layout
  float* ws   = (float*)d_ws;
  float* feat = ws;                                   // NN*HID f32
  u16*  fni   = (u16*)(feat + (size_t)NN * HID);      // NN*HD bf16
  u16*  fnj   = fni + (size_t)NN * HD;                // NN*HD bf16
  u16*  hn    = fnj + (size_t)NN * HD;                // NN*HD bf16
  u16*  efb   = hn + (size_t)NN * HD;                 // NE*HID bf16 (original order)
  u16*  Wt    = efb + (size_t)NE * HID;               // HD*HID bf16
  float* elog = (float*)(Wt + (size_t)HD * HID);      // NE*HEADS f32 (CSR order)
  float* mz   = elog + (size_t)NE * HEADS;            // NN*8 f32
  int* counts = (int*)(mz + (size_t)NN * 8);          // NN
  int* rowptr = counts + NN;                          // NN+1
  int* cursor = rowptr + NN + 1;                      // NN
  int* eidx   = cursor + NN;                          // NE
  int* srcp   = eidx + NE;                            // NE
  int* dstp   = srcp + NE;                            // NE
  float* aggb = (float*)fni;  // overlay fni+fnj; safe: written after edgelogits.

  hipMemsetAsync(counts, 0, sizeof(int) * NN, stream);
  hipMemsetAsync(cursor, 0, sizeof(int) * NN, stream);

  k_embed<<<(NN * 64) / 256, 256, 0, stream>>>(node_feat, W_embed, b_embed, feat, out);
  k_count<<<NE / 256, 256, 0, stream>>>(dst, counts);
  k_scan<<<1, 1024, 0, stream>>>(counts, rowptr);
  k_scatter<<<NE / 256, 256, 0, stream>>>(dst, src, rowptr, cursor, eidx, srcp, dstp);
  k_convert<<<(NE * HID / 4) / 256, 256, 0, stream>>>(edge_feat, efb);

  for (int L = 0; L < 2; ++L) {
    const float* WniL = W_ni + (size_t)L * HID * HD;
    const float* WnjL = W_nj + (size_t)L * HID * HD;
    const float* WfL  = W_fij + (size_t)L * HID * HD;
    const float* WndL = W_node + (size_t)L * HID * HD;
    const float* battL = b_att + (size_t)L * HD;
    const float* attnL = attn + (size_t)L * HEADS * HID;
    const float* WmL  = W_mlp + (size_t)L * HD * HID;
    const float* bmL  = b_mlp + (size_t)L * HID;

    k_prepw<<<(HID * HD) / 256, 256, 0, stream>>>(WfL, Wt);
    k_nodeproj<<<NN / 8, 256, 0, stream>>>(feat, WniL, WnjL, WndL, battL, fni, fnj, hn);
    k_edgelogits<<<2500, 256, 0, stream>>>(efb, eidx, srcp, dstp, fni, fnj, Wt, attnL, elog);
    k_mz<<<(NN * HEADS + 255) / 256, 256, 0, stream>>>(rowptr, elog, mz);
    k_agg<<<(NN * 64) / 256, 256, 0, stream>>>(rowptr, srcp, elog, mz, hn, aggb);
    k_mlp<<<NN / 32, 256, 0, stream>>>(aggb, WmL, bmL, feat, out, 80 + L * 64);
  }
}